// Round 1
// baseline (1141.257 us; speedup 1.0000x reference)
//
#include <hip/hip_runtime.h>

// ---------------------------------------------------------------------------
// GIN 2-layer forward, fp32 baseline.
//   conv(x) = mlp(x + segment_sum(x[src], dst)); mlp = Lin->ReLU->Lin
//   out = conv1(relu(conv0(x)))
// N=50000, E=600000, dims 128->256->256->256->128.
// ---------------------------------------------------------------------------

__global__ void copy_f4(float* __restrict__ dst, const float* __restrict__ src,
                        long long n4) {
  long long i = blockIdx.x * (long long)blockDim.x + threadIdx.x;
  long long stride = (long long)gridDim.x * blockDim.x;
  for (; i < n4; i += stride) {
    ((float4*)dst)[i] = ((const float4*)src)[i];
  }
}

// one thread per (edge, feature): acc[dst*D + f] += x[src*D + f], D = 1<<shift
__global__ void scatter_add(float* __restrict__ acc, const float* __restrict__ x,
                            const int* __restrict__ eidx, int E, int shift,
                            long long total) {
  long long i = blockIdx.x * (long long)blockDim.x + threadIdx.x;
  if (i >= total) return;
  int e = (int)(i >> shift);
  int f = (int)(i & ((1 << shift) - 1));
  int s = eidx[e];      // src row
  int d = eidx[e + E];  // dst row
  atomicAdd(acc + (((long long)d) << shift) + f, x[(((long long)s) << shift) + f]);
}

// C[M,N] = A[M,K] @ B[K,N] + bias, optional ReLU. BM=BN=64, BK=16,
// 256 threads, 4x4 micro-tile per thread. fp32 (no fp32 MFMA on CDNA4).
template <bool RELU>
__global__ __launch_bounds__(256) void gemm_bias(
    const float* __restrict__ A, const float* __restrict__ B,
    const float* __restrict__ bias, float* __restrict__ C,
    int M, int K, int N) {
  const int BM = 64, BN = 64, BK = 16;
  __shared__ float As[BK][BM + 4];  // [k][m], pad 4 keeps float4 alignment
  __shared__ float Bs[BK][BN + 4];  // [k][n]

  int tid = threadIdx.x;
  int tx = tid & 15;   // micro col group
  int ty = tid >> 4;   // micro row group
  int rowBase = blockIdx.y * BM;
  int colBase = blockIdx.x * BN;

  int a_row = tid >> 2;          // 0..63
  int a_k4  = (tid & 3) << 2;    // 0,4,8,12
  int b_k   = tid >> 4;          // 0..15
  int b_c4  = (tid & 15) << 2;   // 0..60

  float acc[4][4] = {{0.f}};

  for (int k0 = 0; k0 < K; k0 += BK) {
    float4 a = make_float4(0.f, 0.f, 0.f, 0.f);
    int gr = rowBase + a_row;
    if (gr < M) a = *(const float4*)(A + (long long)gr * K + k0 + a_k4);
    As[a_k4 + 0][a_row] = a.x;
    As[a_k4 + 1][a_row] = a.y;
    As[a_k4 + 2][a_row] = a.z;
    As[a_k4 + 3][a_row] = a.w;
    float4 b = *(const float4*)(B + (long long)(k0 + b_k) * N + colBase + b_c4);
    *((float4*)&Bs[b_k][b_c4]) = b;
    __syncthreads();
#pragma unroll
    for (int kk = 0; kk < BK; ++kk) {
      float av[4], bv[4];
      *(float4*)av = *(const float4*)&As[kk][ty << 2];
      *(float4*)bv = *(const float4*)&Bs[kk][tx << 2];
#pragma unroll
      for (int i = 0; i < 4; ++i)
#pragma unroll
        for (int j = 0; j < 4; ++j)
          acc[i][j] = fmaf(av[i], bv[j], acc[i][j]);
    }
    __syncthreads();
  }

  float bv4[4];
  *(float4*)bv4 = *(const float4*)(bias + colBase + (tx << 2));
#pragma unroll
  for (int i = 0; i < 4; ++i) {
    int gr = rowBase + (ty << 2) + i;
    if (gr < M) {
      float o[4];
#pragma unroll
      for (int j = 0; j < 4; ++j) {
        o[j] = acc[i][j] + bv4[j];
        if (RELU) o[j] = fmaxf(o[j], 0.f);
      }
      *(float4*)(C + (long long)gr * N + colBase + (tx << 2)) = *(const float4*)o;
    }
  }
}

extern "C" void kernel_launch(void* const* d_in, const int* in_sizes, int n_in,
                              void* d_out, int out_size, void* d_ws, size_t ws_size,
                              hipStream_t stream) {
  const float* x   = (const float*)d_in[0];
  const float* W1a = (const float*)d_in[1];
  const float* b1a = (const float*)d_in[2];
  const float* W2a = (const float*)d_in[3];
  const float* b2a = (const float*)d_in[4];
  const float* W1b = (const float*)d_in[5];
  const float* b1b = (const float*)d_in[6];
  const float* W2b = (const float*)d_in[7];
  const float* b2b = (const float*)d_in[8];
  const int*   ei  = (const int*)d_in[9];  // [2,E] flat: row0=src, row1=dst

  const int Nn = in_sizes[0] / 128;  // 50000 nodes
  const int E  = in_sizes[9] / 2;    // 600000 edges
  float* out = (float*)d_out;

  // workspace: 3 ping-pong buffers of N*256 fp32 (153.6 MB total)
  float* bufA = (float*)d_ws;                    // acc0 (N*128), then h (N*256)
  float* bufB = bufA + (size_t)Nn * 256;         // t, then t2
  float* bufC = bufB + (size_t)Nn * 256;         // acc1

  dim3 blk(256);

  // ---- layer 0: acc0 = x + segment_sum(x[src], dst) ----
  copy_f4<<<2048, blk, 0, stream>>>(bufA, x, (long long)Nn * 128 / 4);
  long long tot0 = (long long)E * 128;
  scatter_add<<<(tot0 + 255) / 256, blk, 0, stream>>>(bufA, x, ei, E, 7, tot0);

  dim3 g256(256 / 64, (Nn + 63) / 64);
  dim3 g128(128 / 64, (Nn + 63) / 64);
  // t = relu(acc0 @ W1a + b1a)
  gemm_bias<true><<<g256, blk, 0, stream>>>(bufA, W1a, b1a, bufB, Nn, 128, 256);
  // h = relu(t @ W2a + b2a)   (fuses the post-conv0 relu)
  gemm_bias<true><<<g256, blk, 0, stream>>>(bufB, W2a, b2a, bufA, Nn, 256, 256);

  // ---- layer 1: acc1 = h + segment_sum(h[src], dst) ----
  copy_f4<<<2048, blk, 0, stream>>>(bufC, bufA, (long long)Nn * 256 / 4);
  long long tot1 = (long long)E * 256;
  scatter_add<<<(tot1 + 255) / 256, blk, 0, stream>>>(bufC, bufA, ei, E, 8, tot1);

  // t2 = relu(acc1 @ W1b + b1b)
  gemm_bias<true><<<g256, blk, 0, stream>>>(bufC, W1b, b1b, bufB, Nn, 256, 256);
  // out = t2 @ W2b + b2b   (no trailing relu)
  gemm_bias<false><<<g128, blk, 0, stream>>>(bufB, W2b, b2b, out, Nn, 256, 128);
}

// Round 2
// 670.484 us; speedup vs baseline: 1.7021x; 1.7021x over previous
//
#include <hip/hip_runtime.h>

// ---------------------------------------------------------------------------
// GIN 2-layer forward.
//   conv(x) = mlp(x + segment_sum(x[src], dst)); mlp = Lin->ReLU->Lin
//   out = conv1(relu(conv0(x)))
// N=50000, E=600000, dims 128->256->256->256->128.
// R1: CSR-gather aggregation (no fp32 atomics, no copy kernel).
// ---------------------------------------------------------------------------

typedef float v4f __attribute__((ext_vector_type(4)));
typedef float v2f __attribute__((ext_vector_type(2)));
template <int N> struct VecT;
template <> struct VecT<2> { using type = v2f; };
template <> struct VecT<4> { using type = v4f; };

__global__ void zero_ints(int* __restrict__ p, int n) {
  int i = blockIdx.x * blockDim.x + threadIdx.x;
  if (i < n) p[i] = 0;
}

// degree histogram over dst
__global__ void hist(const int* __restrict__ eidx, int* __restrict__ deg, int E) {
  int e = blockIdx.x * blockDim.x + threadIdx.x;
  if (e < E) atomicAdd(&deg[eidx[e + E]], 1);
}

// single-block exclusive scan: offs[0..N], pos[i]=offs[i] (mutable cursors)
__global__ __launch_bounds__(1024) void exscan(const int* __restrict__ deg,
                                               int* __restrict__ offs,
                                               int* __restrict__ pos, int Nn) {
  __shared__ int sm[1024];
  __shared__ int s_run;
  int t = threadIdx.x;
  if (t == 0) s_run = 0;
  __syncthreads();
  for (int base = 0; base < Nn; base += 1024) {
    int v = (base + t < Nn) ? deg[base + t] : 0;
    sm[t] = v;
    __syncthreads();
#pragma unroll
    for (int off = 1; off < 1024; off <<= 1) {
      int add = (t >= off) ? sm[t - off] : 0;
      __syncthreads();
      sm[t] += add;
      __syncthreads();
    }
    int run = s_run;
    if (base + t < Nn) {
      int ex = run + sm[t] - v;
      offs[base + t] = ex;
      pos[base + t] = ex;
    }
    __syncthreads();
    if (t == 1023) s_run = run + sm[1023];
    __syncthreads();
  }
  if (t == 0) offs[Nn] = s_run;
}

// esrc[pos[dst]++] = src
__global__ void fill_csr(const int* __restrict__ eidx, int* __restrict__ pos,
                         int* __restrict__ esrc, int E) {
  int e = blockIdx.x * blockDim.x + threadIdx.x;
  if (e < E) {
    int s = eidx[e];
    int d = eidx[e + E];
    int p = atomicAdd(&pos[d], 1);
    esrc[p] = s;
  }
}

// one wave per node: out[i] = x[i] + sum_{s in N(i)} x[s]
template <int D>
__global__ __launch_bounds__(256) void aggregate(
    float* __restrict__ out, const float* __restrict__ x,
    const int* __restrict__ offs, const int* __restrict__ esrc, int Nn) {
  constexpr int VPL = D / 64;  // floats per lane
  using V = typename VecT<VPL>::type;
  int wave = blockIdx.x * 4 + (threadIdx.x >> 6);
  int lane = threadIdx.x & 63;
  if (wave >= Nn) return;
  int beg = offs[wave], end = offs[wave + 1];
  const long long lo = (long long)lane * VPL;
  V acc = *(const V*)(x + (long long)wave * D + lo);  // self term (1+eps)*x, eps=0
  V acc2 = acc - acc;                                 // zero
  int n = beg;
  for (; n + 1 < end; n += 2) {
    int s0 = esrc[n], s1 = esrc[n + 1];
    V v0 = *(const V*)(x + (long long)s0 * D + lo);
    V v1 = *(const V*)(x + (long long)s1 * D + lo);
    acc += v0;
    acc2 += v1;
  }
  if (n < end) {
    int s0 = esrc[n];
    acc += *(const V*)(x + (long long)s0 * D + lo);
  }
  acc += acc2;
  *(V*)(out + (long long)wave * D + lo) = acc;
}

// C[M,N] = A[M,K] @ B[K,N] + bias, optional ReLU. BM=BN=64, BK=16,
// 256 threads, 4x4 micro-tile per thread. fp32 (no fp32 MFMA on CDNA4).
template <bool RELU>
__global__ __launch_bounds__(256) void gemm_bias(
    const float* __restrict__ A, const float* __restrict__ B,
    const float* __restrict__ bias, float* __restrict__ C,
    int M, int K, int N) {
  const int BM = 64, BN = 64, BK = 16;
  __shared__ float As[BK][BM + 4];
  __shared__ float Bs[BK][BN + 4];

  int tid = threadIdx.x;
  int tx = tid & 15;
  int ty = tid >> 4;
  int rowBase = blockIdx.y * BM;
  int colBase = blockIdx.x * BN;

  int a_row = tid >> 2;
  int a_k4  = (tid & 3) << 2;
  int b_k   = tid >> 4;
  int b_c4  = (tid & 15) << 2;

  float acc[4][4] = {{0.f}};

  for (int k0 = 0; k0 < K; k0 += BK) {
    float4 a = make_float4(0.f, 0.f, 0.f, 0.f);
    int gr = rowBase + a_row;
    if (gr < M) a = *(const float4*)(A + (long long)gr * K + k0 + a_k4);
    As[a_k4 + 0][a_row] = a.x;
    As[a_k4 + 1][a_row] = a.y;
    As[a_k4 + 2][a_row] = a.z;
    As[a_k4 + 3][a_row] = a.w;
    float4 b = *(const float4*)(B + (long long)(k0 + b_k) * N + colBase + b_c4);
    *((float4*)&Bs[b_k][b_c4]) = b;
    __syncthreads();
#pragma unroll
    for (int kk = 0; kk < BK; ++kk) {
      float av[4], bv[4];
      *(float4*)av = *(const float4*)&As[kk][ty << 2];
      *(float4*)bv = *(const float4*)&Bs[kk][tx << 2];
#pragma unroll
      for (int i = 0; i < 4; ++i)
#pragma unroll
        for (int j = 0; j < 4; ++j)
          acc[i][j] = fmaf(av[i], bv[j], acc[i][j]);
    }
    __syncthreads();
  }

  float bv4[4];
  *(float4*)bv4 = *(const float4*)(bias + colBase + (tx << 2));
#pragma unroll
  for (int i = 0; i < 4; ++i) {
    int gr = rowBase + (ty << 2) + i;
    if (gr < M) {
      float o[4];
#pragma unroll
      for (int j = 0; j < 4; ++j) {
        o[j] = acc[i][j] + bv4[j];
        if (RELU) o[j] = fmaxf(o[j], 0.f);
      }
      *(float4*)(C + (long long)gr * N + colBase + (tx << 2)) = *(const float4*)o;
    }
  }
}

extern "C" void kernel_launch(void* const* d_in, const int* in_sizes, int n_in,
                              void* d_out, int out_size, void* d_ws, size_t ws_size,
                              hipStream_t stream) {
  const float* x   = (const float*)d_in[0];
  const float* W1a = (const float*)d_in[1];
  const float* b1a = (const float*)d_in[2];
  const float* W2a = (const float*)d_in[3];
  const float* b2a = (const float*)d_in[4];
  const float* W1b = (const float*)d_in[5];
  const float* b1b = (const float*)d_in[6];
  const float* W2b = (const float*)d_in[7];
  const float* b2b = (const float*)d_in[8];
  const int*   ei  = (const int*)d_in[9];  // [2,E]: row0=src, row1=dst

  const int Nn = in_sizes[0] / 128;  // 50000
  const int E  = in_sizes[9] / 2;    // 600000
  float* out = (float*)d_out;

  // workspace layout
  float* bufA = (float*)d_ws;                // N*256 f
  float* bufB = bufA + (size_t)Nn * 256;     // N*256 f
  float* bufC = bufB + (size_t)Nn * 256;     // N*256 f
  int* deg  = (int*)(bufC + (size_t)Nn * 256);
  int* offs = deg + Nn;       // N+1
  int* pos  = offs + Nn + 1;  // N
  int* esrc = pos + Nn;       // E

  dim3 blk(256);

  // ---- CSR build (shared by both layers) ----
  zero_ints<<<(Nn + 255) / 256, blk, 0, stream>>>(deg, Nn);
  hist<<<(E + 255) / 256, blk, 0, stream>>>(ei, deg, E);
  exscan<<<1, 1024, 0, stream>>>(deg, offs, pos, Nn);
  fill_csr<<<(E + 255) / 256, blk, 0, stream>>>(ei, pos, esrc, E);

  int aggBlocks = (Nn + 3) / 4;  // 4 waves per 256-thread block

  // ---- layer 0 ----
  aggregate<128><<<aggBlocks, blk, 0, stream>>>(bufA, x, offs, esrc, Nn);
  dim3 g256(256 / 64, (Nn + 63) / 64);
  dim3 g128(128 / 64, (Nn + 63) / 64);
  gemm_bias<true><<<g256, blk, 0, stream>>>(bufA, W1a, b1a, bufB, Nn, 128, 256);
  gemm_bias<true><<<g256, blk, 0, stream>>>(bufB, W2a, b2a, bufA, Nn, 256, 256);

  // ---- layer 1 ----
  aggregate<256><<<aggBlocks, blk, 0, stream>>>(bufC, bufA, offs, esrc, Nn);
  gemm_bias<true><<<g256, blk, 0, stream>>>(bufC, W1b, b1b, bufB, Nn, 256, 256);
  gemm_bias<false><<<g128, blk, 0, stream>>>(bufB, W2b, b2b, out, Nn, 256, 128);
}

// Round 3
// 449.176 us; speedup vs baseline: 2.5408x; 1.4927x over previous
//
#include <hip/hip_runtime.h>

// ---------------------------------------------------------------------------
// GIN 2-layer forward. R3: bf16 MFMA GEMMs (16x16x32), bf16 dataflow,
// CSR-gather aggregation, faster scan.
//   conv(x) = mlp(x + segment_sum(x[src], dst)); mlp = Lin->ReLU->Lin
// N=50000, E=600000, dims 128->256->256->256->128.
// ---------------------------------------------------------------------------

typedef __bf16 bf16x8 __attribute__((ext_vector_type(8)));
typedef float f32x4 __attribute__((ext_vector_type(4)));
typedef unsigned short u16x4 __attribute__((ext_vector_type(4)));
typedef unsigned short u16x2 __attribute__((ext_vector_type(2)));
typedef unsigned int uint32;

__device__ __forceinline__ unsigned short f2bf(float f) {
  uint32 u = __builtin_bit_cast(uint32, f);
  u += 0x7FFFu + ((u >> 16) & 1u);  // RNE
  return (unsigned short)(u >> 16);
}
__device__ __forceinline__ float bf2f(unsigned short h) {
  return __builtin_bit_cast(float, (uint32)h << 16);
}

#define G2L16(gp, lp)                                                        \
  __builtin_amdgcn_global_load_lds(                                          \
      (const __attribute__((address_space(1))) void*)(gp),                   \
      (__attribute__((address_space(3))) void*)(lp), 16, 0, 0)

// ---------------------------- CSR build ------------------------------------
__global__ void zero_ints(int* __restrict__ p, int n) {
  int i = blockIdx.x * blockDim.x + threadIdx.x;
  if (i < n) p[i] = 0;
}

__global__ void hist(const int* __restrict__ eidx, int* __restrict__ deg, int E) {
  int e = blockIdx.x * blockDim.x + threadIdx.x;
  if (e < E) atomicAdd(&deg[eidx[e + E]], 1);
}

// single-block chunked exclusive scan (~20 barriers total)
__global__ __launch_bounds__(1024) void exscan(const int* __restrict__ deg,
                                               int* __restrict__ offs,
                                               int* __restrict__ pos, int Nn) {
  __shared__ int sm[1024];
  int t = threadIdx.x;
  int chunk = (Nn + 1023) / 1024;
  int b = t * chunk;
  int e = min(b + chunk, Nn);
  int s = 0;
  for (int i = b; i < e; ++i) s += deg[i];
  sm[t] = s;
  __syncthreads();
#pragma unroll
  for (int off = 1; off < 1024; off <<= 1) {
    int add = (t >= off) ? sm[t - off] : 0;
    __syncthreads();
    sm[t] += add;
    __syncthreads();
  }
  int run = (t == 0) ? 0 : sm[t - 1];
  for (int i = b; i < e; ++i) {
    offs[i] = run;
    pos[i] = run;
    run += deg[i];
  }
  if (t == 1023) offs[Nn] = sm[1023];
}

__global__ void fill_csr(const int* __restrict__ eidx, int* __restrict__ pos,
                         int* __restrict__ esrc, int E) {
  int e = blockIdx.x * blockDim.x + threadIdx.x;
  if (e < E) {
    int s = eidx[e];
    int d = eidx[e + E];
    int p = atomicAdd(&pos[d], 1);
    esrc[p] = s;
  }
}

// ------------------------- aggregation -------------------------------------
// layer 0: out(bf16) = x(f32) self + sum neighbors. D=128, one wave per node.
__global__ __launch_bounds__(256) void agg_f32_bf16_128(
    unsigned short* __restrict__ out, const float* __restrict__ x,
    const int* __restrict__ offs, const int* __restrict__ esrc, int Nn) {
  int node = blockIdx.x * 4 + (threadIdx.x >> 6);
  int lane = threadIdx.x & 63;
  if (node >= Nn) return;
  int beg = offs[node], end = offs[node + 1];
  const int lo = lane * 2;
  float2 a0 = *(const float2*)(x + (long long)node * 128 + lo);
  float2 a1 = make_float2(0.f, 0.f);
  int n = beg;
  for (; n + 1 < end; n += 2) {
    int s0 = esrc[n], s1 = esrc[n + 1];
    float2 v0 = *(const float2*)(x + (long long)s0 * 128 + lo);
    float2 v1 = *(const float2*)(x + (long long)s1 * 128 + lo);
    a0.x += v0.x; a0.y += v0.y;
    a1.x += v1.x; a1.y += v1.y;
  }
  if (n < end) {
    float2 v0 = *(const float2*)(x + (long long)esrc[n] * 128 + lo);
    a0.x += v0.x; a0.y += v0.y;
  }
  a0.x += a1.x; a0.y += a1.y;
  u16x2 o; o.x = f2bf(a0.x); o.y = f2bf(a0.y);
  *(u16x2*)(out + (long long)node * 128 + lo) = o;
}

// layer 1: out(bf16) = h(bf16) self + sum neighbors. D=256, one wave per node.
__global__ __launch_bounds__(256) void agg_bf16_bf16_256(
    unsigned short* __restrict__ out, const unsigned short* __restrict__ h,
    const int* __restrict__ offs, const int* __restrict__ esrc, int Nn) {
  int node = blockIdx.x * 4 + (threadIdx.x >> 6);
  int lane = threadIdx.x & 63;
  if (node >= Nn) return;
  int beg = offs[node], end = offs[node + 1];
  const int lo = lane * 4;
  u16x4 sv = *(const u16x4*)(h + (long long)node * 256 + lo);
  float a0 = bf2f(sv.x), a1 = bf2f(sv.y), a2 = bf2f(sv.z), a3 = bf2f(sv.w);
  float b0 = 0.f, b1 = 0.f, b2 = 0.f, b3 = 0.f;
  int n = beg;
  for (; n + 1 < end; n += 2) {
    u16x4 v0 = *(const u16x4*)(h + (long long)esrc[n] * 256 + lo);
    u16x4 v1 = *(const u16x4*)(h + (long long)esrc[n + 1] * 256 + lo);
    a0 += bf2f(v0.x); a1 += bf2f(v0.y); a2 += bf2f(v0.z); a3 += bf2f(v0.w);
    b0 += bf2f(v1.x); b1 += bf2f(v1.y); b2 += bf2f(v1.z); b3 += bf2f(v1.w);
  }
  if (n < end) {
    u16x4 v0 = *(const u16x4*)(h + (long long)esrc[n] * 256 + lo);
    a0 += bf2f(v0.x); a1 += bf2f(v0.y); a2 += bf2f(v0.z); a3 += bf2f(v0.w);
  }
  u16x4 o;
  o.x = f2bf(a0 + b0); o.y = f2bf(a1 + b1); o.z = f2bf(a2 + b2); o.w = f2bf(a3 + b3);
  *(u16x4*)(out + (long long)node * 256 + lo) = o;
}

// ------------------- weight transpose + bf16 convert ------------------------
// W[K][N] f32 -> WT[N][K] bf16
__global__ void transpose_w(const float* __restrict__ W,
                            unsigned short* __restrict__ WT, int K, int N) {
  int i = blockIdx.x * 256 + threadIdx.x;
  if (i >= K * N) return;
  int k = i / N, n = i - k * N;
  WT[(long long)n * K + k] = f2bf(W[i]);
}

// ----------------------------- MFMA GEMM ------------------------------------
// C[M,N] = A[M,K]@B[K,N] + bias (opt ReLU). A bf16 [M][K], BT bf16 [N][K].
// BM=BN=128, BK=32. 256 threads = 4 waves in 2x2, each wave 64x64 (4x4 tiles
// of 16x16x32 MFMA). global_load_lds width-16 staging.
template <bool RELU, bool OUT_BF16>
__global__ __launch_bounds__(256) void gemm_mfma(
    const unsigned short* __restrict__ A, const unsigned short* __restrict__ BT,
    const float* __restrict__ bias, void* __restrict__ C, int M, int K, int N) {
  __shared__ unsigned short As[128 * 32];
  __shared__ unsigned short Bs[128 * 32];
  const int tid = threadIdx.x;
  const int wave = tid >> 6, lane = tid & 63;
  const int wm = wave & 1, wn = wave >> 1;
  const int quad = lane >> 4, l16 = lane & 15;
  const int rowBase = blockIdx.y * 128;
  const int colBase = blockIdx.x * 128;

  // staging: wave w covers tile rows 32w..32w+31 (stages 2w, 2w+1)
  const int srow = wave * 32 + (lane >> 2);   // rows for stage 2w; +16 for 2w+1
  const int koff = (lane & 3) * 8;            // ushort offset within 64B row
  long long ra0 = min(rowBase + srow, M - 1);
  long long ra1 = min(rowBase + srow + 16, M - 1);
  const unsigned short* ga0 = A + ra0 * K + koff;
  const unsigned short* ga1 = A + ra1 * K + koff;
  const unsigned short* gb0 = BT + (long long)(colBase + srow) * K + koff;
  const unsigned short* gb1 = BT + (long long)(colBase + srow + 16) * K + koff;
  unsigned short* la0 = As + wave * 1024;
  unsigned short* la1 = As + wave * 1024 + 512;
  unsigned short* lb0 = Bs + wave * 1024;
  unsigned short* lb1 = Bs + wave * 1024 + 512;

  f32x4 acc[4][4] = {};

  for (int k0 = 0; k0 < K; k0 += 32) {
    G2L16(ga0, la0);
    G2L16(ga1, la1);
    G2L16(gb0, lb0);
    G2L16(gb1, lb1);
    ga0 += 32; ga1 += 32; gb0 += 32; gb1 += 32;
    __syncthreads();  // drains LDS-DMA (compiler emits vmcnt(0) before barrier)

    bf16x8 af[4], bfr[4];
    const int arow = wm * 64 + l16;
    const int brow = wn * 64 + l16;
#pragma unroll
    for (int mi = 0; mi < 4; ++mi)
      af[mi] = *(const bf16x8*)(As + (arow + mi * 16) * 32 + quad * 8);
#pragma unroll
    for (int ni = 0; ni < 4; ++ni)
      bfr[ni] = *(const bf16x8*)(Bs + (brow + ni * 16) * 32 + quad * 8);
#pragma unroll
    for (int mi = 0; mi < 4; ++mi)
#pragma unroll
      for (int ni = 0; ni < 4; ++ni)
        acc[mi][ni] = __builtin_amdgcn_mfma_f32_16x16x32_bf16(
            af[mi], bfr[ni], acc[mi][ni], 0, 0, 0);
    __syncthreads();  // readers done before next stage overwrites
  }

  // epilogue: C/D layout col=lane&15, row=quad*4+reg
  float bias_v[4];
#pragma unroll
  for (int ni = 0; ni < 4; ++ni)
    bias_v[ni] = bias[colBase + wn * 64 + ni * 16 + l16];
#pragma unroll
  for (int mi = 0; mi < 4; ++mi) {
#pragma unroll
    for (int r = 0; r < 4; ++r) {
      int row = rowBase + wm * 64 + mi * 16 + quad * 4 + r;
      if (row < M) {
#pragma unroll
        for (int ni = 0; ni < 4; ++ni) {
          float o = acc[mi][ni][r] + bias_v[ni];
          if (RELU) o = fmaxf(o, 0.f);
          int col = colBase + wn * 64 + ni * 16 + l16;
          if (OUT_BF16)
            ((unsigned short*)C)[(long long)row * N + col] = f2bf(o);
          else
            ((float*)C)[(long long)row * N + col] = o;
        }
      }
    }
  }
}

// ---------------------------------------------------------------------------
extern "C" void kernel_launch(void* const* d_in, const int* in_sizes, int n_in,
                              void* d_out, int out_size, void* d_ws, size_t ws_size,
                              hipStream_t stream) {
  const float* x   = (const float*)d_in[0];
  const float* W1a = (const float*)d_in[1];
  const float* b1a = (const float*)d_in[2];
  const float* W2a = (const float*)d_in[3];
  const float* b2a = (const float*)d_in[4];
  const float* W1b = (const float*)d_in[5];
  const float* b1b = (const float*)d_in[6];
  const float* W2b = (const float*)d_in[7];
  const float* b2b = (const float*)d_in[8];
  const int*   ei  = (const int*)d_in[9];  // [2,E]: row0=src, row1=dst

  const int Nn = in_sizes[0] / 128;  // 50000
  const int E  = in_sizes[9] / 2;    // 600000
  float* out = (float*)d_out;

  // workspace
  unsigned short* t   = (unsigned short*)d_ws;     // N*256 bf16
  unsigned short* h   = t  + (size_t)Nn * 256;     // N*256
  unsigned short* g0  = h  + (size_t)Nn * 256;     // N*128
  unsigned short* g1  = g0 + (size_t)Nn * 128;     // N*256
  unsigned short* t2  = g1 + (size_t)Nn * 256;     // N*256
  unsigned short* w1t = t2 + (size_t)Nn * 256;     // 256*128
  unsigned short* w2t = w1t + 256 * 128;           // 256*256
  unsigned short* w3t = w2t + 256 * 256;           // 256*256
  unsigned short* w4t = w3t + 256 * 256;           // 128*256
  int* deg  = (int*)(w4t + 128 * 256);
  int* offs = deg + Nn;        // N+1
  int* pos  = offs + Nn + 1;   // N
  int* esrc = pos + Nn;        // E

  dim3 blk(256);

  // CSR build
  zero_ints<<<(Nn + 255) / 256, blk, 0, stream>>>(deg, Nn);
  hist<<<(E + 255) / 256, blk, 0, stream>>>(ei, deg, E);
  exscan<<<1, 1024, 0, stream>>>(deg, offs, pos, Nn);
  fill_csr<<<(E + 255) / 256, blk, 0, stream>>>(ei, pos, esrc, E);

  // weight transposes (tiny)
  transpose_w<<<(128 * 256 + 255) / 256, blk, 0, stream>>>(W1a, w1t, 128, 256);
  transpose_w<<<(256 * 256 + 255) / 256, blk, 0, stream>>>(W2a, w2t, 256, 256);
  transpose_w<<<(256 * 256 + 255) / 256, blk, 0, stream>>>(W1b, w3t, 256, 256);
  transpose_w<<<(256 * 128 + 255) / 256, blk, 0, stream>>>(W2b, w4t, 256, 128);

  int aggBlocks = (Nn + 3) / 4;
  int gy = (Nn + 127) / 128;

  // layer 0
  agg_f32_bf16_128<<<aggBlocks, blk, 0, stream>>>(g0, x, offs, esrc, Nn);
  gemm_mfma<true, true><<<dim3(2, gy), blk, 0, stream>>>(g0, w1t, b1a, t, Nn, 128, 256);
  gemm_mfma<true, true><<<dim3(2, gy), blk, 0, stream>>>(t, w2t, b2a, h, Nn, 256, 256);

  // layer 1
  agg_bf16_bf16_256<<<aggBlocks, blk, 0, stream>>>(g1, h, offs, esrc, Nn);
  gemm_mfma<true, true><<<dim3(2, gy), blk, 0, stream>>>(g1, w3t, b1b, t2, Nn, 256, 256);
  gemm_mfma<false, false><<<dim3(1, gy), blk, 0, stream>>>(t2, w4t, b2b, out, Nn, 256, 128);
}

// Round 4
// 347.086 us; speedup vs baseline: 3.2881x; 1.2941x over previous
//
#include <hip/hip_runtime.h>

// ---------------------------------------------------------------------------
// GIN 2-layer forward. R4: hierarchical CSR scan (kills 110us single-block
// exscan). bf16 MFMA GEMMs (16x16x32), bf16 dataflow, CSR-gather aggregation.
//   conv(x) = mlp(x + segment_sum(x[src], dst)); mlp = Lin->ReLU->Lin
// N=50000, E=600000, dims 128->256->256->256->128.
// ---------------------------------------------------------------------------

typedef __bf16 bf16x8 __attribute__((ext_vector_type(8)));
typedef float f32x4 __attribute__((ext_vector_type(4)));
typedef unsigned short u16x4 __attribute__((ext_vector_type(4)));
typedef unsigned short u16x2 __attribute__((ext_vector_type(2)));
typedef unsigned int uint32;

__device__ __forceinline__ unsigned short f2bf(float f) {
  uint32 u = __builtin_bit_cast(uint32, f);
  u += 0x7FFFu + ((u >> 16) & 1u);  // RNE
  return (unsigned short)(u >> 16);
}
__device__ __forceinline__ float bf2f(unsigned short h) {
  return __builtin_bit_cast(float, (uint32)h << 16);
}

#define G2L16(gp, lp)                                                        \
  __builtin_amdgcn_global_load_lds(                                          \
      (const __attribute__((address_space(1))) void*)(gp),                   \
      (__attribute__((address_space(3))) void*)(lp), 16, 0, 0)

// ---------------------------- CSR build ------------------------------------
__global__ void zero_ints(int* __restrict__ p, int n) {
  int i = blockIdx.x * blockDim.x + threadIdx.x;
  if (i < n) p[i] = 0;
}

__global__ void hist(const int* __restrict__ eidx, int* __restrict__ deg, int E) {
  int e = blockIdx.x * blockDim.x + threadIdx.x;
  if (e < E) atomicAdd(&deg[eidx[e + E]], 1);
}

// pass 1: per-block (256 elems) sums
__global__ __launch_bounds__(256) void block_sums(const int* __restrict__ deg,
                                                  int* __restrict__ bsum, int Nn) {
  __shared__ int sm[256];
  int t = threadIdx.x;
  int i = blockIdx.x * 256 + t;
  sm[t] = (i < Nn) ? deg[i] : 0;
  __syncthreads();
#pragma unroll
  for (int off = 128; off > 0; off >>= 1) {
    if (t < off) sm[t] += sm[t + off];
    __syncthreads();
  }
  if (t == 0) bsum[blockIdx.x] = sm[0];
}

// pass 2: single block exclusive-scans nb (<=256) block sums in place
__global__ __launch_bounds__(256) void scan_bsums(int* __restrict__ bsum, int nb) {
  __shared__ int sm[256];
  int t = threadIdx.x;
  int v = (t < nb) ? bsum[t] : 0;
  sm[t] = v;
  __syncthreads();
#pragma unroll
  for (int off = 1; off < 256; off <<= 1) {
    int add = (t >= off) ? sm[t - off] : 0;
    __syncthreads();
    sm[t] += add;
    __syncthreads();
  }
  if (t < nb) bsum[t] = sm[t] - v;  // exclusive
}

// pass 3: per-block exclusive scan + block offset -> offs, pos; offs[Nn]
__global__ __launch_bounds__(256) void block_scan(const int* __restrict__ deg,
                                                  const int* __restrict__ bsum,
                                                  int* __restrict__ offs,
                                                  int* __restrict__ pos, int Nn) {
  __shared__ int sm[256];
  int t = threadIdx.x;
  int i = blockIdx.x * 256 + t;
  int v = (i < Nn) ? deg[i] : 0;
  sm[t] = v;
  __syncthreads();
#pragma unroll
  for (int off = 1; off < 256; off <<= 1) {
    int add = (t >= off) ? sm[t - off] : 0;
    __syncthreads();
    sm[t] += add;
    __syncthreads();
  }
  int ex = bsum[blockIdx.x] + sm[t] - v;
  if (i < Nn) {
    offs[i] = ex;
    pos[i] = ex;
    if (i == Nn - 1) offs[Nn] = ex + v;
  }
}

__global__ void fill_csr(const int* __restrict__ eidx, int* __restrict__ pos,
                         int* __restrict__ esrc, int E) {
  int e = blockIdx.x * blockDim.x + threadIdx.x;
  if (e < E) {
    int s = eidx[e];
    int d = eidx[e + E];
    int p = atomicAdd(&pos[d], 1);
    esrc[p] = s;
  }
}

// ------------------------- aggregation -------------------------------------
// layer 0: out(bf16) = x(f32) self + sum neighbors. D=128, one wave per node.
__global__ __launch_bounds__(256) void agg_f32_bf16_128(
    unsigned short* __restrict__ out, const float* __restrict__ x,
    const int* __restrict__ offs, const int* __restrict__ esrc, int Nn) {
  int node = blockIdx.x * 4 + (threadIdx.x >> 6);
  int lane = threadIdx.x & 63;
  if (node >= Nn) return;
  int beg = offs[node], end = offs[node + 1];
  const int lo = lane * 2;
  float2 a0 = *(const float2*)(x + (long long)node * 128 + lo);
  float2 a1 = make_float2(0.f, 0.f);
  int n = beg;
  for (; n + 1 < end; n += 2) {
    int s0 = esrc[n], s1 = esrc[n + 1];
    float2 v0 = *(const float2*)(x + (long long)s0 * 128 + lo);
    float2 v1 = *(const float2*)(x + (long long)s1 * 128 + lo);
    a0.x += v0.x; a0.y += v0.y;
    a1.x += v1.x; a1.y += v1.y;
  }
  if (n < end) {
    float2 v0 = *(const float2*)(x + (long long)esrc[n] * 128 + lo);
    a0.x += v0.x; a0.y += v0.y;
  }
  a0.x += a1.x; a0.y += a1.y;
  u16x2 o; o.x = f2bf(a0.x); o.y = f2bf(a0.y);
  *(u16x2*)(out + (long long)node * 128 + lo) = o;
}

// layer 1: out(bf16) = h(bf16) self + sum neighbors. D=256, one wave per node.
__global__ __launch_bounds__(256) void agg_bf16_bf16_256(
    unsigned short* __restrict__ out, const unsigned short* __restrict__ h,
    const int* __restrict__ offs, const int* __restrict__ esrc, int Nn) {
  int node = blockIdx.x * 4 + (threadIdx.x >> 6);
  int lane = threadIdx.x & 63;
  if (node >= Nn) return;
  int beg = offs[node], end = offs[node + 1];
  const int lo = lane * 4;
  u16x4 sv = *(const u16x4*)(h + (long long)node * 256 + lo);
  float a0 = bf2f(sv.x), a1 = bf2f(sv.y), a2 = bf2f(sv.z), a3 = bf2f(sv.w);
  float b0 = 0.f, b1 = 0.f, b2 = 0.f, b3 = 0.f;
  int n = beg;
  for (; n + 1 < end; n += 2) {
    u16x4 v0 = *(const u16x4*)(h + (long long)esrc[n] * 256 + lo);
    u16x4 v1 = *(const u16x4*)(h + (long long)esrc[n + 1] * 256 + lo);
    a0 += bf2f(v0.x); a1 += bf2f(v0.y); a2 += bf2f(v0.z); a3 += bf2f(v0.w);
    b0 += bf2f(v1.x); b1 += bf2f(v1.y); b2 += bf2f(v1.z); b3 += bf2f(v1.w);
  }
  if (n < end) {
    u16x4 v0 = *(const u16x4*)(h + (long long)esrc[n] * 256 + lo);
    a0 += bf2f(v0.x); a1 += bf2f(v0.y); a2 += bf2f(v0.z); a3 += bf2f(v0.w);
  }
  u16x4 o;
  o.x = f2bf(a0 + b0); o.y = f2bf(a1 + b1); o.z = f2bf(a2 + b2); o.w = f2bf(a3 + b3);
  *(u16x4*)(out + (long long)node * 256 + lo) = o;
}

// ------------------- weight transpose + bf16 convert ------------------------
// W[K][N] f32 -> WT[N][K] bf16
__global__ void transpose_w(const float* __restrict__ W,
                            unsigned short* __restrict__ WT, int K, int N) {
  int i = blockIdx.x * 256 + threadIdx.x;
  if (i >= K * N) return;
  int k = i / N, n = i - k * N;
  WT[(long long)n * K + k] = f2bf(W[i]);
}

// ----------------------------- MFMA GEMM ------------------------------------
// C[M,N] = A[M,K]@B[K,N] + bias (opt ReLU). A bf16 [M][K], BT bf16 [N][K].
// BM=BN=128, BK=32. 256 threads = 4 waves in 2x2, each wave 64x64 (4x4 tiles
// of 16x16x32 MFMA). global_load_lds width-16 staging.
template <bool RELU, bool OUT_BF16>
__global__ __launch_bounds__(256) void gemm_mfma(
    const unsigned short* __restrict__ A, const unsigned short* __restrict__ BT,
    const float* __restrict__ bias, void* __restrict__ C, int M, int K, int N) {
  __shared__ unsigned short As[128 * 32];
  __shared__ unsigned short Bs[128 * 32];
  const int tid = threadIdx.x;
  const int wave = tid >> 6, lane = tid & 63;
  const int wm = wave & 1, wn = wave >> 1;
  const int quad = lane >> 4, l16 = lane & 15;
  const int rowBase = blockIdx.y * 128;
  const int colBase = blockIdx.x * 128;

  const int srow = wave * 32 + (lane >> 2);
  const int koff = (lane & 3) * 8;
  long long ra0 = min(rowBase + srow, M - 1);
  long long ra1 = min(rowBase + srow + 16, M - 1);
  const unsigned short* ga0 = A + ra0 * K + koff;
  const unsigned short* ga1 = A + ra1 * K + koff;
  const unsigned short* gb0 = BT + (long long)(colBase + srow) * K + koff;
  const unsigned short* gb1 = BT + (long long)(colBase + srow + 16) * K + koff;
  unsigned short* la0 = As + wave * 1024;
  unsigned short* la1 = As + wave * 1024 + 512;
  unsigned short* lb0 = Bs + wave * 1024;
  unsigned short* lb1 = Bs + wave * 1024 + 512;

  f32x4 acc[4][4] = {};

  for (int k0 = 0; k0 < K; k0 += 32) {
    G2L16(ga0, la0);
    G2L16(ga1, la1);
    G2L16(gb0, lb0);
    G2L16(gb1, lb1);
    ga0 += 32; ga1 += 32; gb0 += 32; gb1 += 32;
    __syncthreads();

    bf16x8 af[4], bfr[4];
    const int arow = wm * 64 + l16;
    const int brow = wn * 64 + l16;
#pragma unroll
    for (int mi = 0; mi < 4; ++mi)
      af[mi] = *(const bf16x8*)(As + (arow + mi * 16) * 32 + quad * 8);
#pragma unroll
    for (int ni = 0; ni < 4; ++ni)
      bfr[ni] = *(const bf16x8*)(Bs + (brow + ni * 16) * 32 + quad * 8);
#pragma unroll
    for (int mi = 0; mi < 4; ++mi)
#pragma unroll
      for (int ni = 0; ni < 4; ++ni)
        acc[mi][ni] = __builtin_amdgcn_mfma_f32_16x16x32_bf16(
            af[mi], bfr[ni], acc[mi][ni], 0, 0, 0);
    __syncthreads();
  }

  float bias_v[4];
#pragma unroll
  for (int ni = 0; ni < 4; ++ni)
    bias_v[ni] = bias[colBase + wn * 64 + ni * 16 + l16];
#pragma unroll
  for (int mi = 0; mi < 4; ++mi) {
#pragma unroll
    for (int r = 0; r < 4; ++r) {
      int row = rowBase + wm * 64 + mi * 16 + quad * 4 + r;
      if (row < M) {
#pragma unroll
        for (int ni = 0; ni < 4; ++ni) {
          float o = acc[mi][ni][r] + bias_v[ni];
          if (RELU) o = fmaxf(o, 0.f);
          int col = colBase + wn * 64 + ni * 16 + l16;
          if (OUT_BF16)
            ((unsigned short*)C)[(long long)row * N + col] = f2bf(o);
          else
            ((float*)C)[(long long)row * N + col] = o;
        }
      }
    }
  }
}

// ---------------------------------------------------------------------------
extern "C" void kernel_launch(void* const* d_in, const int* in_sizes, int n_in,
                              void* d_out, int out_size, void* d_ws, size_t ws_size,
                              hipStream_t stream) {
  const float* x   = (const float*)d_in[0];
  const float* W1a = (const float*)d_in[1];
  const float* b1a = (const float*)d_in[2];
  const float* W2a = (const float*)d_in[3];
  const float* b2a = (const float*)d_in[4];
  const float* W1b = (const float*)d_in[5];
  const float* b1b = (const float*)d_in[6];
  const float* W2b = (const float*)d_in[7];
  const float* b2b = (const float*)d_in[8];
  const int*   ei  = (const int*)d_in[9];  // [2,E]: row0=src, row1=dst

  const int Nn = in_sizes[0] / 128;  // 50000
  const int E  = in_sizes[9] / 2;    // 600000
  float* out = (float*)d_out;

  // workspace
  unsigned short* t   = (unsigned short*)d_ws;     // N*256 bf16
  unsigned short* h   = t  + (size_t)Nn * 256;     // N*256
  unsigned short* g0  = h  + (size_t)Nn * 256;     // N*128
  unsigned short* g1  = g0 + (size_t)Nn * 128;     // N*256
  unsigned short* t2  = g1 + (size_t)Nn * 256;     // N*256
  unsigned short* w1t = t2 + (size_t)Nn * 256;     // 256*128
  unsigned short* w2t = w1t + 256 * 128;           // 256*256
  unsigned short* w3t = w2t + 256 * 256;           // 256*256
  unsigned short* w4t = w3t + 256 * 256;           // 128*256
  int* deg  = (int*)(w4t + 128 * 256);
  int* offs = deg + Nn;        // N+1
  int* pos  = offs + Nn + 1;   // N
  int* esrc = pos + Nn;        // E
  int* bsum = esrc + E;        // ~196

  dim3 blk(256);
  int nb = (Nn + 255) / 256;  // 196 scan blocks

  // CSR build
  zero_ints<<<(Nn + 255) / 256, blk, 0, stream>>>(deg, Nn);
  hist<<<(E + 255) / 256, blk, 0, stream>>>(ei, deg, E);
  block_sums<<<nb, blk, 0, stream>>>(deg, bsum, Nn);
  scan_bsums<<<1, blk, 0, stream>>>(bsum, nb);
  block_scan<<<nb, blk, 0, stream>>>(deg, bsum, offs, pos, Nn);
  fill_csr<<<(E + 255) / 256, blk, 0, stream>>>(ei, pos, esrc, E);

  // weight transposes (tiny)
  transpose_w<<<(128 * 256 + 255) / 256, blk, 0, stream>>>(W1a, w1t, 128, 256);
  transpose_w<<<(256 * 256 + 255) / 256, blk, 0, stream>>>(W2a, w2t, 256, 256);
  transpose_w<<<(256 * 256 + 255) / 256, blk, 0, stream>>>(W1b, w3t, 256, 256);
  transpose_w<<<(256 * 128 + 255) / 256, blk, 0, stream>>>(W2b, w4t, 256, 128);

  int aggBlocks = (Nn + 3) / 4;
  int gy = (Nn + 127) / 128;

  // layer 0
  agg_f32_bf16_128<<<aggBlocks, blk, 0, stream>>>(g0, x, offs, esrc, Nn);
  gemm_mfma<true, true><<<dim3(2, gy), blk, 0, stream>>>(g0, w1t, b1a, t, Nn, 128, 256);
  gemm_mfma<true, true><<<dim3(2, gy), blk, 0, stream>>>(t, w2t, b2a, h, Nn, 256, 256);

  // layer 1
  agg_bf16_bf16_256<<<aggBlocks, blk, 0, stream>>>(g1, h, offs, esrc, Nn);
  gemm_mfma<true, true><<<dim3(2, gy), blk, 0, stream>>>(g1, w3t, b1b, t2, Nn, 256, 256);
  gemm_mfma<false, false><<<dim3(1, gy), blk, 0, stream>>>(t2, w4t, b2b, out, Nn, 256, 128);
}

// Round 5
// 316.794 us; speedup vs baseline: 3.6025x; 1.0956x over previous
//
#include <hip/hip_runtime.h>

// ---------------------------------------------------------------------------
// GIN 2-layer forward. R5: bf16 gather for layer-0 agg (pre-cast x), unroll-4
// aggregation loops (4 row-loads in flight), fused weight transposes.
// bf16 MFMA GEMMs (16x16x32), CSR-gather aggregation, hierarchical scan.
//   conv(x) = mlp(x + segment_sum(x[src], dst)); mlp = Lin->ReLU->Lin
// N=50000, E=600000, dims 128->256->256->256->128.
// ---------------------------------------------------------------------------

typedef __bf16 bf16x8 __attribute__((ext_vector_type(8)));
typedef float f32x4 __attribute__((ext_vector_type(4)));
typedef unsigned short u16x4 __attribute__((ext_vector_type(4)));
typedef unsigned short u16x2 __attribute__((ext_vector_type(2)));
typedef unsigned int uint32;

__device__ __forceinline__ unsigned short f2bf(float f) {
  uint32 u = __builtin_bit_cast(uint32, f);
  u += 0x7FFFu + ((u >> 16) & 1u);  // RNE
  return (unsigned short)(u >> 16);
}
__device__ __forceinline__ float bf2f(unsigned short h) {
  return __builtin_bit_cast(float, (uint32)h << 16);
}

#define G2L16(gp, lp)                                                        \
  __builtin_amdgcn_global_load_lds(                                          \
      (const __attribute__((address_space(1))) void*)(gp),                   \
      (__attribute__((address_space(3))) void*)(lp), 16, 0, 0)

// ---------------------------- CSR build ------------------------------------
__global__ void zero_ints(int* __restrict__ p, int n) {
  int i = blockIdx.x * blockDim.x + threadIdx.x;
  if (i < n) p[i] = 0;
}

__global__ void hist(const int* __restrict__ eidx, int* __restrict__ deg, int E) {
  int e = blockIdx.x * blockDim.x + threadIdx.x;
  if (e < E) atomicAdd(&deg[eidx[e + E]], 1);
}

__global__ __launch_bounds__(256) void block_sums(const int* __restrict__ deg,
                                                  int* __restrict__ bsum, int Nn) {
  __shared__ int sm[256];
  int t = threadIdx.x;
  int i = blockIdx.x * 256 + t;
  sm[t] = (i < Nn) ? deg[i] : 0;
  __syncthreads();
#pragma unroll
  for (int off = 128; off > 0; off >>= 1) {
    if (t < off) sm[t] += sm[t + off];
    __syncthreads();
  }
  if (t == 0) bsum[blockIdx.x] = sm[0];
}

__global__ __launch_bounds__(256) void scan_bsums(int* __restrict__ bsum, int nb) {
  __shared__ int sm[256];
  int t = threadIdx.x;
  int v = (t < nb) ? bsum[t] : 0;
  sm[t] = v;
  __syncthreads();
#pragma unroll
  for (int off = 1; off < 256; off <<= 1) {
    int add = (t >= off) ? sm[t - off] : 0;
    __syncthreads();
    sm[t] += add;
    __syncthreads();
  }
  if (t < nb) bsum[t] = sm[t] - v;  // exclusive
}

__global__ __launch_bounds__(256) void block_scan(const int* __restrict__ deg,
                                                  const int* __restrict__ bsum,
                                                  int* __restrict__ offs,
                                                  int* __restrict__ pos, int Nn) {
  __shared__ int sm[256];
  int t = threadIdx.x;
  int i = blockIdx.x * 256 + t;
  int v = (i < Nn) ? deg[i] : 0;
  sm[t] = v;
  __syncthreads();
#pragma unroll
  for (int off = 1; off < 256; off <<= 1) {
    int add = (t >= off) ? sm[t - off] : 0;
    __syncthreads();
    sm[t] += add;
    __syncthreads();
  }
  int ex = bsum[blockIdx.x] + sm[t] - v;
  if (i < Nn) {
    offs[i] = ex;
    pos[i] = ex;
    if (i == Nn - 1) offs[Nn] = ex + v;
  }
}

__global__ void fill_csr(const int* __restrict__ eidx, int* __restrict__ pos,
                         int* __restrict__ esrc, int E) {
  int e = blockIdx.x * blockDim.x + threadIdx.x;
  if (e < E) {
    int s = eidx[e];
    int d = eidx[e + E];
    int p = atomicAdd(&pos[d], 1);
    esrc[p] = s;
  }
}

// ------------------------ x -> bf16 pre-cast --------------------------------
__global__ void cast_f32_bf16(const float* __restrict__ src,
                              unsigned short* __restrict__ dst, long long n4) {
  long long i = blockIdx.x * (long long)blockDim.x + threadIdx.x;
  long long stride = (long long)gridDim.x * blockDim.x;
  for (; i < n4; i += stride) {
    float4 v = ((const float4*)src)[i];
    u16x4 o;
    o.x = f2bf(v.x); o.y = f2bf(v.y); o.z = f2bf(v.z); o.w = f2bf(v.w);
    ((u16x4*)dst)[i] = o;
  }
}

// ------------------------- aggregation -------------------------------------
// D=128 bf16 gather: one wave per node, u16x2/lane, unroll 4.
__global__ __launch_bounds__(256) void agg_bf16_128(
    unsigned short* __restrict__ out, const unsigned short* __restrict__ xb,
    const int* __restrict__ offs, const int* __restrict__ esrc, int Nn) {
  int node = blockIdx.x * 4 + (threadIdx.x >> 6);
  int lane = threadIdx.x & 63;
  if (node >= Nn) return;
  int beg = offs[node], end = offs[node + 1];
  const unsigned short* xp = xb + lane * 2;
  u16x2 sv = *(const u16x2*)(xp + (long long)node * 128);
  float a0 = bf2f(sv.x), a1 = bf2f(sv.y);
  float b0 = 0.f, b1 = 0.f, c0 = 0.f, c1 = 0.f, d0 = 0.f, d1 = 0.f;
  int n = beg;
  for (; n + 3 < end; n += 4) {
    u16x2 v0 = *(const u16x2*)(xp + (long long)esrc[n] * 128);
    u16x2 v1 = *(const u16x2*)(xp + (long long)esrc[n + 1] * 128);
    u16x2 v2 = *(const u16x2*)(xp + (long long)esrc[n + 2] * 128);
    u16x2 v3 = *(const u16x2*)(xp + (long long)esrc[n + 3] * 128);
    a0 += bf2f(v0.x); a1 += bf2f(v0.y);
    b0 += bf2f(v1.x); b1 += bf2f(v1.y);
    c0 += bf2f(v2.x); c1 += bf2f(v2.y);
    d0 += bf2f(v3.x); d1 += bf2f(v3.y);
  }
  for (; n < end; ++n) {
    u16x2 v0 = *(const u16x2*)(xp + (long long)esrc[n] * 128);
    a0 += bf2f(v0.x); a1 += bf2f(v0.y);
  }
  a0 += b0 + c0 + d0;
  a1 += b1 + c1 + d1;
  u16x2 o; o.x = f2bf(a0); o.y = f2bf(a1);
  *(u16x2*)(out + (long long)node * 128 + lane * 2) = o;
}

// D=256 bf16 gather: one wave per node, u16x4/lane, unroll 4.
__global__ __launch_bounds__(256) void agg_bf16_256(
    unsigned short* __restrict__ out, const unsigned short* __restrict__ h,
    const int* __restrict__ offs, const int* __restrict__ esrc, int Nn) {
  int node = blockIdx.x * 4 + (threadIdx.x >> 6);
  int lane = threadIdx.x & 63;
  if (node >= Nn) return;
  int beg = offs[node], end = offs[node + 1];
  const unsigned short* hp = h + lane * 4;
  u16x4 sv = *(const u16x4*)(hp + (long long)node * 256);
  float a0 = bf2f(sv.x), a1 = bf2f(sv.y), a2 = bf2f(sv.z), a3 = bf2f(sv.w);
  float b0 = 0, b1 = 0, b2 = 0, b3 = 0;
  float c0 = 0, c1 = 0, c2 = 0, c3 = 0;
  float d0 = 0, d1 = 0, d2 = 0, d3 = 0;
  int n = beg;
  for (; n + 3 < end; n += 4) {
    u16x4 v0 = *(const u16x4*)(hp + (long long)esrc[n] * 256);
    u16x4 v1 = *(const u16x4*)(hp + (long long)esrc[n + 1] * 256);
    u16x4 v2 = *(const u16x4*)(hp + (long long)esrc[n + 2] * 256);
    u16x4 v3 = *(const u16x4*)(hp + (long long)esrc[n + 3] * 256);
    a0 += bf2f(v0.x); a1 += bf2f(v0.y); a2 += bf2f(v0.z); a3 += bf2f(v0.w);
    b0 += bf2f(v1.x); b1 += bf2f(v1.y); b2 += bf2f(v1.z); b3 += bf2f(v1.w);
    c0 += bf2f(v2.x); c1 += bf2f(v2.y); c2 += bf2f(v2.z); c3 += bf2f(v2.w);
    d0 += bf2f(v3.x); d1 += bf2f(v3.y); d2 += bf2f(v3.z); d3 += bf2f(v3.w);
  }
  for (; n < end; ++n) {
    u16x4 v0 = *(const u16x4*)(hp + (long long)esrc[n] * 256);
    a0 += bf2f(v0.x); a1 += bf2f(v0.y); a2 += bf2f(v0.z); a3 += bf2f(v0.w);
  }
  a0 += b0 + c0 + d0; a1 += b1 + c1 + d1;
  a2 += b2 + c2 + d2; a3 += b3 + c3 + d3;
  u16x4 o;
  o.x = f2bf(a0); o.y = f2bf(a1); o.z = f2bf(a2); o.w = f2bf(a3);
  *(u16x4*)(out + (long long)node * 256 + lane * 4) = o;
}

// ------------- fused weight transpose + bf16 convert (all 4) ----------------
// W[K][N] f32 -> WT[N][K] bf16 for the 4 weight matrices in one launch.
__global__ void transpose_all(const float* __restrict__ W1a, const float* __restrict__ W2a,
                              const float* __restrict__ W1b, const float* __restrict__ W2b,
                              unsigned short* __restrict__ w1t, unsigned short* __restrict__ w2t,
                              unsigned short* __restrict__ w3t, unsigned short* __restrict__ w4t) {
  int i = blockIdx.x * 256 + threadIdx.x;  // 0 .. 196607
  const float* W;
  unsigned short* WT;
  int K, N, j;
  if (i < 32768) {            // W1a: 128x256
    W = W1a; WT = w1t; K = 128; N = 256; j = i;
  } else if (i < 98304) {     // W2a: 256x256
    W = W2a; WT = w2t; K = 256; N = 256; j = i - 32768;
  } else if (i < 163840) {    // W1b: 256x256
    W = W1b; WT = w3t; K = 256; N = 256; j = i - 98304;
  } else {                    // W2b: 256x128
    W = W2b; WT = w4t; K = 256; N = 128; j = i - 163840;
  }
  int k = j / N, n = j - k * N;
  WT[n * K + k] = f2bf(W[j]);
}

// ----------------------------- MFMA GEMM ------------------------------------
// C[M,N] = A[M,K]@B[K,N] + bias (opt ReLU). A bf16 [M][K], BT bf16 [N][K].
// BM=BN=128, BK=32. 256 threads = 4 waves in 2x2, each wave 64x64 (4x4 tiles
// of 16x16x32 MFMA). global_load_lds width-16 staging.
template <bool RELU, bool OUT_BF16>
__global__ __launch_bounds__(256) void gemm_mfma(
    const unsigned short* __restrict__ A, const unsigned short* __restrict__ BT,
    const float* __restrict__ bias, void* __restrict__ C, int M, int K, int N) {
  __shared__ unsigned short As[128 * 32];
  __shared__ unsigned short Bs[128 * 32];
  const int tid = threadIdx.x;
  const int wave = tid >> 6, lane = tid & 63;
  const int wm = wave & 1, wn = wave >> 1;
  const int quad = lane >> 4, l16 = lane & 15;
  const int rowBase = blockIdx.y * 128;
  const int colBase = blockIdx.x * 128;

  const int srow = wave * 32 + (lane >> 2);
  const int koff = (lane & 3) * 8;
  long long ra0 = min(rowBase + srow, M - 1);
  long long ra1 = min(rowBase + srow + 16, M - 1);
  const unsigned short* ga0 = A + ra0 * K + koff;
  const unsigned short* ga1 = A + ra1 * K + koff;
  const unsigned short* gb0 = BT + (long long)(colBase + srow) * K + koff;
  const unsigned short* gb1 = BT + (long long)(colBase + srow + 16) * K + koff;
  unsigned short* la0 = As + wave * 1024;
  unsigned short* la1 = As + wave * 1024 + 512;
  unsigned short* lb0 = Bs + wave * 1024;
  unsigned short* lb1 = Bs + wave * 1024 + 512;

  f32x4 acc[4][4] = {};

  for (int k0 = 0; k0 < K; k0 += 32) {
    G2L16(ga0, la0);
    G2L16(ga1, la1);
    G2L16(gb0, lb0);
    G2L16(gb1, lb1);
    ga0 += 32; ga1 += 32; gb0 += 32; gb1 += 32;
    __syncthreads();

    bf16x8 af[4], bfr[4];
    const int arow = wm * 64 + l16;
    const int brow = wn * 64 + l16;
#pragma unroll
    for (int mi = 0; mi < 4; ++mi)
      af[mi] = *(const bf16x8*)(As + (arow + mi * 16) * 32 + quad * 8);
#pragma unroll
    for (int ni = 0; ni < 4; ++ni)
      bfr[ni] = *(const bf16x8*)(Bs + (brow + ni * 16) * 32 + quad * 8);
#pragma unroll
    for (int mi = 0; mi < 4; ++mi)
#pragma unroll
      for (int ni = 0; ni < 4; ++ni)
        acc[mi][ni] = __builtin_amdgcn_mfma_f32_16x16x32_bf16(
            af[mi], bfr[ni], acc[mi][ni], 0, 0, 0);
    __syncthreads();
  }

  float bias_v[4];
#pragma unroll
  for (int ni = 0; ni < 4; ++ni)
    bias_v[ni] = bias[colBase + wn * 64 + ni * 16 + l16];
#pragma unroll
  for (int mi = 0; mi < 4; ++mi) {
#pragma unroll
    for (int r = 0; r < 4; ++r) {
      int row = rowBase + wm * 64 + mi * 16 + quad * 4 + r;
      if (row < M) {
#pragma unroll
        for (int ni = 0; ni < 4; ++ni) {
          float o = acc[mi][ni][r] + bias_v[ni];
          if (RELU) o = fmaxf(o, 0.f);
          int col = colBase + wn * 64 + ni * 16 + l16;
          if (OUT_BF16)
            ((unsigned short*)C)[(long long)row * N + col] = f2bf(o);
          else
            ((float*)C)[(long long)row * N + col] = o;
        }
      }
    }
  }
}

// ---------------------------------------------------------------------------
extern "C" void kernel_launch(void* const* d_in, const int* in_sizes, int n_in,
                              void* d_out, int out_size, void* d_ws, size_t ws_size,
                              hipStream_t stream) {
  const float* x   = (const float*)d_in[0];
  const float* W1a = (const float*)d_in[1];
  const float* b1a = (const float*)d_in[2];
  const float* W2a = (const float*)d_in[3];
  const float* b2a = (const float*)d_in[4];
  const float* W1b = (const float*)d_in[5];
  const float* b1b = (const float*)d_in[6];
  const float* W2b = (const float*)d_in[7];
  const float* b2b = (const float*)d_in[8];
  const int*   ei  = (const int*)d_in[9];  // [2,E]: row0=src, row1=dst

  const int Nn = in_sizes[0] / 128;  // 50000
  const int E  = in_sizes[9] / 2;    // 600000
  float* out = (float*)d_out;

  // workspace
  unsigned short* t   = (unsigned short*)d_ws;     // N*256 bf16
  unsigned short* h   = t  + (size_t)Nn * 256;     // N*256
  unsigned short* g0  = h  + (size_t)Nn * 256;     // N*128
  unsigned short* g1  = g0 + (size_t)Nn * 128;     // N*256
  unsigned short* t2  = g1 + (size_t)Nn * 256;     // N*256
  unsigned short* xb  = t2 + (size_t)Nn * 256;     // N*128
  unsigned short* w1t = xb + (size_t)Nn * 128;     // 256*128
  unsigned short* w2t = w1t + 256 * 128;           // 256*256
  unsigned short* w3t = w2t + 256 * 256;           // 256*256
  unsigned short* w4t = w3t + 256 * 256;           // 128*256
  int* deg  = (int*)(w4t + 128 * 256);
  int* offs = deg + Nn;        // N+1
  int* pos  = offs + Nn + 1;   // N
  int* esrc = pos + Nn;        // E
  int* bsum = esrc + E;        // ~196

  dim3 blk(256);
  int nb = (Nn + 255) / 256;  // 196 scan blocks

  // CSR build
  zero_ints<<<(Nn + 255) / 256, blk, 0, stream>>>(deg, Nn);
  hist<<<(E + 255) / 256, blk, 0, stream>>>(ei, deg, E);
  block_sums<<<nb, blk, 0, stream>>>(deg, bsum, Nn);
  scan_bsums<<<1, blk, 0, stream>>>(bsum, nb);
  block_scan<<<nb, blk, 0, stream>>>(deg, bsum, offs, pos, Nn);
  fill_csr<<<(E + 255) / 256, blk, 0, stream>>>(ei, pos, esrc, E);

  // x -> bf16, weight transposes
  cast_f32_bf16<<<1024, blk, 0, stream>>>(x, xb, (long long)Nn * 128 / 4);
  transpose_all<<<768, blk, 0, stream>>>(W1a, W2a, W1b, W2b, w1t, w2t, w3t, w4t);

  int aggBlocks = (Nn + 3) / 4;
  int gy = (Nn + 127) / 128;

  // layer 0
  agg_bf16_128<<<aggBlocks, blk, 0, stream>>>(g0, xb, offs, esrc, Nn);
  gemm_mfma<true, true><<<dim3(2, gy), blk, 0, stream>>>(g0, w1t, b1a, t, Nn, 128, 256);
  gemm_mfma<true, true><<<dim3(2, gy), blk, 0, stream>>>(t, w2t, b2a, h, Nn, 256, 256);

  // layer 1
  agg_bf16_256<<<aggBlocks, blk, 0, stream>>>(g1, h, offs, esrc, Nn);
  gemm_mfma<true, true><<<dim3(2, gy), blk, 0, stream>>>(g1, w3t, b1b, t2, Nn, 256, 256);
  gemm_mfma<false, false><<<dim3(1, gy), blk, 0, stream>>>(t2, w4t, b2b, out, Nn, 256, 128);
}